// Round 1
// baseline (11220.236 us; speedup 1.0000x reference)
//
#include <hip/hip_runtime.h>
#include <cstddef>

#define DD 256
#define HH 512
#define TM 16
#define NSEG 7168     // 1024*7 nodes that receive edges
#define NNODE 8192    // 1024*8

// ---------------- inner GEMM helpers ----------------
// xs: LDS tile [32 k][16 rows]; accumulate acc[TM][4] over 32 k-steps.
__device__ __forceinline__ void gemm_chunk4(const float (*xs)[16],
                                            const float* __restrict__ Wp,
                                            int c0, float acc[TM][4]) {
  #pragma unroll 8
  for (int kk = 0; kk < 32; ++kk) {
    const float4 wv = *(const float4*)(Wp + (size_t)kk * HH + c0);
    float xr[16];
    *(float4*)&xr[0]  = *(const float4*)&xs[kk][0];
    *(float4*)&xr[4]  = *(const float4*)&xs[kk][4];
    *(float4*)&xr[8]  = *(const float4*)&xs[kk][8];
    *(float4*)&xr[12] = *(const float4*)&xs[kk][12];
    #pragma unroll
    for (int r = 0; r < TM; ++r) {
      acc[r][0] = fmaf(xr[r], wv.x, acc[r][0]);
      acc[r][1] = fmaf(xr[r], wv.y, acc[r][1]);
      acc[r][2] = fmaf(xr[r], wv.z, acc[r][2]);
      acc[r][3] = fmaf(xr[r], wv.w, acc[r][3]);
    }
  }
}

__device__ __forceinline__ void gemm_chunk2(const float (*xs)[16],
                                            const float* __restrict__ Wp,
                                            int c0, float acc[TM][2]) {
  #pragma unroll 8
  for (int kk = 0; kk < 32; ++kk) {
    const float2 wv = *(const float2*)(Wp + (size_t)kk * DD + c0);
    float xr[16];
    *(float4*)&xr[0]  = *(const float4*)&xs[kk][0];
    *(float4*)&xr[4]  = *(const float4*)&xs[kk][4];
    *(float4*)&xr[8]  = *(const float4*)&xs[kk][8];
    *(float4*)&xr[12] = *(const float4*)&xs[kk][12];
    #pragma unroll
    for (int r = 0; r < TM; ++r) {
      acc[r][0] = fmaf(xr[r], wv.x, acc[r][0]);
      acc[r][1] = fmaf(xr[r], wv.y, acc[r][1]);
    }
  }
}

__device__ __forceinline__ void stage16x32(float (*xs)[16], int rr, int kk4,
                                           const float* __restrict__ src) {
  const float4 xv = *(const float4*)src;
  xs[kk4 + 0][rr] = xv.x;
  xs[kk4 + 1][rr] = xv.y;
  xs[kk4 + 2][rr] = xv.z;
  xs[kk4 + 3][rr] = xv.w;
}

// ---------------- edge layer 1: H1 = relu([flat[row]|attr[row]|flat[col]] @ W1 + b1) ----------------
__global__ __launch_bounds__(128)
void edge_l1(const float* __restrict__ flat, const float* __restrict__ attr,
             const float* __restrict__ W1, const float* __restrict__ b1,
             float* __restrict__ H, int e0, int nE) {
  const int t = threadIdx.x;
  const int c0 = t * 4;
  const int ebase = blockIdx.x * TM;
  const int rr = t >> 3, kk4 = (t & 7) * 4;
  __shared__ __align__(16) float xs[32][16];
  __shared__ int rowi[TM], coli[TM];

  if (t < TM) {
    int e = e0 + ebase + t;
    int emax = e0 + nE - 1;
    if (e > emax) e = emax;
    int b = e / 42, p = e - b * 42;
    int i = p / 6, tt = p - i * 6;
    int j = tt + (tt >= i ? 1 : 0);
    rowi[t] = b * 7 + i;
    coli[t] = b * 7 + j;
  }
  __syncthreads();
  const int myrow = rowi[rr], mycol = coli[rr];

  float acc[TM][4];
  #pragma unroll
  for (int r = 0; r < TM; ++r) { acc[r][0] = 0.f; acc[r][1] = 0.f; acc[r][2] = 0.f; acc[r][3] = 0.f; }

  #pragma unroll 1
  for (int seg = 0; seg < 3; ++seg) {
    const float* base;
    if (seg == 0) base = flat + (size_t)myrow * DD;
    else if (seg == 1) { if (attr == nullptr) continue; base = attr + (size_t)myrow * DD; }
    else base = flat + (size_t)mycol * DD;
    const float* wseg = W1 + (size_t)seg * DD * HH;
    #pragma unroll 1
    for (int k0 = 0; k0 < DD; k0 += 32) {
      __syncthreads();
      stage16x32(xs, rr, kk4, base + k0 + kk4);
      __syncthreads();
      gemm_chunk4(xs, wseg + (size_t)k0 * HH, c0, acc);
    }
  }
  const float4 bv = *(const float4*)(b1 + c0);
  #pragma unroll
  for (int r = 0; r < TM; ++r) {
    int le = ebase + r;
    if (le < nE) {
      float4 o;
      o.x = fmaxf(acc[r][0] + bv.x, 0.f);
      o.y = fmaxf(acc[r][1] + bv.y, 0.f);
      o.z = fmaxf(acc[r][2] + bv.z, 0.f);
      o.w = fmaxf(acc[r][3] + bv.w, 0.f);
      *(float4*)(H + (size_t)le * HH + c0) = o;
    }
  }
}

// ---------------- layer 2 with LayerNorm: Y = relu(LN(X@W + b)*g + bn), K=N=512 (in-place safe) ----------------
__global__ __launch_bounds__(128)
void mlp_l2_ln(const float* __restrict__ X, const float* __restrict__ W,
               const float* __restrict__ bb, const float* __restrict__ gg,
               const float* __restrict__ bn, float* __restrict__ Y) {
  const int t = threadIdx.x;
  const int c0 = t * 4;
  const int m0 = blockIdx.x * TM;
  const int rr = t >> 3, kk4 = (t & 7) * 4;
  __shared__ __align__(16) float xs[32][16];
  __shared__ float red[2][TM][128];
  __shared__ float mu[TM], rsd[TM];

  float acc[TM][4];
  #pragma unroll
  for (int r = 0; r < TM; ++r) { acc[r][0] = 0.f; acc[r][1] = 0.f; acc[r][2] = 0.f; acc[r][3] = 0.f; }

  const float* xrow = X + (size_t)(m0 + rr) * HH + kk4;
  #pragma unroll 1
  for (int k0 = 0; k0 < HH; k0 += 32) {
    __syncthreads();
    stage16x32(xs, rr, kk4, xrow + k0);
    __syncthreads();
    gemm_chunk4(xs, W + (size_t)k0 * HH, c0, acc);
  }

  const float4 bv = *(const float4*)(bb + c0);
  #pragma unroll
  for (int r = 0; r < TM; ++r) {
    acc[r][0] += bv.x; acc[r][1] += bv.y; acc[r][2] += bv.z; acc[r][3] += bv.w;
    red[0][r][t] = acc[r][0] + acc[r][1] + acc[r][2] + acc[r][3];
    red[1][r][t] = acc[r][0]*acc[r][0] + acc[r][1]*acc[r][1] + acc[r][2]*acc[r][2] + acc[r][3]*acc[r][3];
  }
  __syncthreads();
  for (int s = 64; s > 0; s >>= 1) {
    if (t < s) {
      #pragma unroll
      for (int r = 0; r < TM; ++r) {
        red[0][r][t] += red[0][r][t + s];
        red[1][r][t] += red[1][r][t + s];
      }
    }
    __syncthreads();
  }
  if (t < TM) {
    float m = red[0][t][0] * (1.f / HH);
    float v = red[1][t][0] * (1.f / HH) - m * m;
    mu[t] = m;
    rsd[t] = rsqrtf(v + 1e-5f);
  }
  __syncthreads();
  const float4 gv = *(const float4*)(gg + c0);
  const float4 bnv = *(const float4*)(bn + c0);
  #pragma unroll
  for (int r = 0; r < TM; ++r) {
    float4 o;
    o.x = fmaxf((acc[r][0] - mu[r]) * rsd[r] * gv.x + bnv.x, 0.f);
    o.y = fmaxf((acc[r][1] - mu[r]) * rsd[r] * gv.y + bnv.y, 0.f);
    o.z = fmaxf((acc[r][2] - mu[r]) * rsd[r] * gv.z + bnv.z, 0.f);
    o.w = fmaxf((acc[r][3] - mu[r]) * rsd[r] * gv.w + bnv.w, 0.f);
    *(float4*)(Y + (size_t)(m0 + r) * HH + c0) = o;
  }
}

// ---------------- sum 6 contiguous H2 rows per segment ----------------
__global__ void h2_sum(const float* __restrict__ H2, float* __restrict__ S, int total) {
  int idx = blockIdx.x * blockDim.x + threadIdx.x;
  if (idx >= total) return;
  int c = idx & (HH - 1);
  int ln = idx >> 9;
  const float* p = H2 + (size_t)ln * 6 * HH + c;
  float s = p[0] + p[HH] + p[2 * HH] + p[3 * HH] + p[4 * HH] + p[5 * HH];
  S[(size_t)ln * HH + c] = s;
}

// ---------------- agg = S @ e_w3 + 6*e_b3 (rows<NSEG), 0 otherwise; in-place on S ----------------
__global__ __launch_bounds__(128)
void gemm_agg(const float* __restrict__ S, const float* __restrict__ W,
              const float* __restrict__ bb, float* __restrict__ Y) {
  const int t = threadIdx.x;
  const int c0 = t * 4;
  const int m0 = blockIdx.x * TM;
  if (m0 >= NSEG) {  // no edges: agg exactly 0 (also keeps tail clean every round)
    #pragma unroll
    for (int r = 0; r < TM; ++r) {
      float4 z; z.x = 0.f; z.y = 0.f; z.z = 0.f; z.w = 0.f;
      *(float4*)(Y + (size_t)(m0 + r) * HH + c0) = z;
    }
    return;
  }
  const int rr = t >> 3, kk4 = (t & 7) * 4;
  __shared__ __align__(16) float xs[32][16];
  float acc[TM][4];
  #pragma unroll
  for (int r = 0; r < TM; ++r) { acc[r][0] = 0.f; acc[r][1] = 0.f; acc[r][2] = 0.f; acc[r][3] = 0.f; }
  const float* xrow = S + (size_t)(m0 + rr) * HH + kk4;
  #pragma unroll 1
  for (int k0 = 0; k0 < HH; k0 += 32) {
    __syncthreads();
    stage16x32(xs, rr, kk4, xrow + k0);
    __syncthreads();
    gemm_chunk4(xs, W + (size_t)k0 * HH, c0, acc);
  }
  const float4 bv = *(const float4*)(bb + c0);
  #pragma unroll
  for (int r = 0; r < TM; ++r) {
    float4 o;
    o.x = acc[r][0] + 6.f * bv.x;
    o.y = acc[r][1] + 6.f * bv.y;
    o.z = acc[r][2] + 6.f * bv.z;
    o.w = acc[r][3] + 6.f * bv.w;
    *(float4*)(Y + (size_t)(m0 + r) * HH + c0) = o;
  }
}

// ---------------- node layer 1: G = relu(flat@W1a + av@W1b + agg@W1c + b1); in-place on agg ----------------
__global__ __launch_bounds__(128)
void node_l1(const float* __restrict__ flat, const float* __restrict__ agg,
             const int* __restrict__ action, const float* __restrict__ W1,
             const float* __restrict__ b1, float* __restrict__ G) {
  const int t = threadIdx.x;
  const int c0 = t * 4;
  const int m0 = blockIdx.x * TM;
  const int rr = t >> 3, kk4 = (t & 7) * 4;
  __shared__ __align__(16) float xs[32][16];
  float acc[TM][4];
  #pragma unroll
  for (int r = 0; r < TM; ++r) { acc[r][0] = 0.f; acc[r][1] = 0.f; acc[r][2] = 0.f; acc[r][3] = 0.f; }

  // segment 0: flat (K = 256), W rows [0,256)
  const float* xrow = flat + (size_t)(m0 + rr) * DD + kk4;
  #pragma unroll 1
  for (int k0 = 0; k0 < DD; k0 += 32) {
    __syncthreads();
    stage16x32(xs, rr, kk4, xrow + k0);
    __syncthreads();
    gemm_chunk4(xs, W1 + (size_t)k0 * HH, c0, acc);
  }
  // segment 2: agg (K = 512), W rows [260,772)
  const float* arow = agg + (size_t)(m0 + rr) * HH + kk4;
  #pragma unroll 1
  for (int k0 = 0; k0 < HH; k0 += 32) {
    __syncthreads();
    stage16x32(xs, rr, kk4, arow + k0);
    __syncthreads();
    gemm_chunk4(xs, W1 + (size_t)(260 + k0) * HH, c0, acc);
  }
  // segment 1: one-hot action (round 0 only), W rows [256,260)
  if (action != nullptr) {
    #pragma unroll
    for (int r = 0; r < TM; ++r) {
      int a = action[(m0 + r) >> 3];
      const float4 wv = *(const float4*)(W1 + (size_t)(256 + a) * HH + c0);
      acc[r][0] += wv.x; acc[r][1] += wv.y; acc[r][2] += wv.z; acc[r][3] += wv.w;
    }
  }
  const float4 bv = *(const float4*)(b1 + c0);
  #pragma unroll
  for (int r = 0; r < TM; ++r) {
    float4 o;
    o.x = fmaxf(acc[r][0] + bv.x, 0.f);
    o.y = fmaxf(acc[r][1] + bv.y, 0.f);
    o.z = fmaxf(acc[r][2] + bv.z, 0.f);
    o.w = fmaxf(acc[r][3] + bv.w, 0.f);
    *(float4*)(G + (size_t)(m0 + r) * HH + c0) = o;
  }
}

// ---------------- node layer 3 + residual: node = G2@W3 + b3; flat += node ----------------
__global__ __launch_bounds__(128)
void node_l3_res(const float* __restrict__ G2, const float* __restrict__ W3,
                 const float* __restrict__ b3, float* __restrict__ node,
                 float* __restrict__ flat) {
  const int t = threadIdx.x;
  const int c0 = t * 2;
  const int m0 = blockIdx.x * TM;
  const int rr = t >> 3, kk4 = (t & 7) * 4;
  __shared__ __align__(16) float xs[32][16];
  float acc[TM][2];
  #pragma unroll
  for (int r = 0; r < TM; ++r) { acc[r][0] = 0.f; acc[r][1] = 0.f; }
  const float* xrow = G2 + (size_t)(m0 + rr) * HH + kk4;
  #pragma unroll 1
  for (int k0 = 0; k0 < HH; k0 += 32) {
    __syncthreads();
    stage16x32(xs, rr, kk4, xrow + k0);
    __syncthreads();
    gemm_chunk2(xs, W3 + (size_t)k0 * DD, c0, acc);
  }
  const float2 bv = *(const float2*)(b3 + c0);
  #pragma unroll
  for (int r = 0; r < TM; ++r) {
    float2 z;
    z.x = acc[r][0] + bv.x;
    z.y = acc[r][1] + bv.y;
    *(float2*)(node + (size_t)(m0 + r) * DD + c0) = z;
    float2 f = *(const float2*)(flat + (size_t)(m0 + r) * DD + c0);
    f.x += z.x; f.y += z.y;
    *(float2*)(flat + (size_t)(m0 + r) * DD + c0) = f;
  }
}

// ---------------- launcher ----------------
extern "C" void kernel_launch(void* const* d_in, const int* in_sizes, int n_in,
                              void* d_out, int out_size, void* d_ws, size_t ws_size,
                              hipStream_t stream) {
  (void)in_sizes; (void)n_in; (void)out_size;
  const float* states = (const float*)d_in[0];
  const int*   action = (const int*)d_in[1];
  const float* e_w1 = (const float*)d_in[2];
  const float* e_b1 = (const float*)d_in[3];
  const float* e_w2 = (const float*)d_in[4];
  const float* e_b2 = (const float*)d_in[5];
  const float* e_g  = (const float*)d_in[6];
  const float* e_bn = (const float*)d_in[7];
  const float* e_w3 = (const float*)d_in[8];
  const float* e_b3 = (const float*)d_in[9];
  const float* n_w1 = (const float*)d_in[10];
  const float* n_b1 = (const float*)d_in[11];
  const float* n_w2 = (const float*)d_in[12];
  const float* n_b2 = (const float*)d_in[13];
  const float* n_g  = (const float*)d_in[14];
  const float* n_bn = (const float*)d_in[15];
  const float* n_w3 = (const float*)d_in[16];
  const float* n_b3 = (const float*)d_in[17];

  float* flat = (float*)d_out;                    // [8192][256]
  float* node = (float*)d_ws;                     // [8192][256]
  float* S    = node + (size_t)NNODE * DD;        // [8192][512]
  float* H    = S + (size_t)NNODE * HH;           // [edges_per_chunk][512]

  const size_t fixedB = ((size_t)NNODE * DD + (size_t)NNODE * HH) * 4;
  int nchunk = 1;
  for (; nchunk < 128; nchunk <<= 1) {
    size_t need = fixedB + (size_t)(43008 / nchunk) * HH * 4;
    if (need <= ws_size) break;
  }
  const int spc = 1024 / nchunk;  // samples per chunk
  const int epc = spc * 42;       // edges per chunk

  hipMemcpyAsync(flat, states, (size_t)NNODE * DD * 4, hipMemcpyDeviceToDevice, stream);

  for (int round = 0; round < 8; ++round) {
    const float* attr = (round == 0) ? nullptr : node;
    for (int ch = 0; ch < nchunk; ++ch) {
      const int e0 = ch * epc;
      edge_l1<<<epc / TM, 128, 0, stream>>>(flat, attr, e_w1, e_b1, H, e0, epc);
      mlp_l2_ln<<<epc / TM, 128, 0, stream>>>(H, e_w2, e_b2, e_g, e_bn, H);
      const int nout = spc * 7 * HH;
      h2_sum<<<(nout + 255) / 256, 256, 0, stream>>>(H, S + (size_t)ch * spc * 7 * HH, nout);
    }
    gemm_agg<<<NNODE / TM, 128, 0, stream>>>(S, e_w3, e_b3, S);
    node_l1<<<NNODE / TM, 128, 0, stream>>>(flat, S, (round == 0) ? action : nullptr, n_w1, n_b1, S);
    mlp_l2_ln<<<NNODE / TM, 128, 0, stream>>>(S, n_w2, n_b2, n_g, n_bn, S);
    node_l3_res<<<NNODE / TM, 128, 0, stream>>>(S, n_w3, n_b3, node, flat);
  }
}

// Round 2
// 3311.675 us; speedup vs baseline: 3.3881x; 3.3881x over previous
//
#include <hip/hip_runtime.h>
#include <cstddef>

typedef _Float16 f16x8 __attribute__((ext_vector_type(8)));
typedef float f32x4 __attribute__((ext_vector_type(4)));
typedef unsigned short ushort_t;

#define SCL 4096.f
#define ISCL (1.f / 4096.f)
#define NSEG 7168
#define NNODE 8192

enum { EP_NONE = 0, EP_BIAS = 1, EP_LN = 2, EP_AGG = 3, EP_NL1 = 4, EP_NL3 = 5 };

// ---------------- weight prepack: W[k][n] fp32 -> fragment-native f16 hi/lo ----------------
// packed layout: [kc][nt][64 lanes][16]: lane = ((k>>3)&3)*16 + (n&15), elem j = k&7 (hi), 8+j (lo)
__global__ __launch_bounds__(256)
void prepack(const float* __restrict__ W, ushort_t* __restrict__ P,
             int koff, int kcnt, int N, int NTOT) {
  int idx = blockIdx.x * 256 + threadIdx.x;
  if (idx >= kcnt * N) return;
  int k = idx / N;
  int n = idx - k * N;
  float w = W[idx];
  _Float16 h = (_Float16)w;
  _Float16 l = (_Float16)((w - (float)h) * SCL);
  int kg = koff + k;
  int kc = kg >> 5, j = kg & 7;
  int lam = ((kg >> 3) & 3) * 16 + (n & 15);
  int nt = n >> 4;
  size_t o = (((size_t)kc * NTOT + nt) * 64 + lam) * 16;
  P[o + j] = __builtin_bit_cast(ushort_t, h);
  P[o + 8 + j] = __builtin_bit_cast(ushort_t, l);
}

// ---------------- unified MFMA GEMM: Y = epilogue(X @ W + ...), 16 rows/block, full N in-block ----
// X is fp32, split to f16 hi/lo during LDS staging; W pre-packed hi/lo.
// EDGE=1: X row e = relu(S[row(e)] + T[col(e)]).
template <int NTOT, int NCT, int EPI, int EDGE>
__global__ __launch_bounds__(256)
void gemm16(const float* __restrict__ X1, int ld1, int nph1,
            const float* __restrict__ X2, int ld2, int nph2,
            const float* __restrict__ Sm, const float* __restrict__ Tm,
            const ushort_t* __restrict__ P,
            const float* __restrict__ bias,
            const float* __restrict__ gg, const float* __restrict__ bnp,
            const int* __restrict__ action, const float* __restrict__ wact,
            float* __restrict__ Y, float* __restrict__ Yres,
            int m0base) {
  const int u = threadIdx.x;
  const int N = NTOT * 16;
  const int mY = blockIdx.x * 16;  // row block in Y / X
  if (EPI == EP_AGG && mY >= NSEG) {
    f32x4* dst = (f32x4*)(Y + (size_t)mY * N);
    #pragma unroll
    for (int i = 0; i < 8; ++i) dst[u + 256 * i] = (f32x4){0.f, 0.f, 0.f, 0.f};
    return;
  }
  const int lane = u & 63;
  const int w = u >> 6;

  __shared__ ushort_t lA[4 * 64 * 16];
  __shared__ int eRow[16], eCol[16];
  __shared__ float redS[16][5], redQ[16][5], mu[16], rsd[16];

  if (EDGE) {
    if (u < 16) {
      int e = m0base + mY + u;
      int b = e / 42, p = e - b * 42;
      int i = p / 6, t = p - i * 6;
      int j = t + (t >= i ? 1 : 0);
      eRow[u] = b * 7 + i;
      eCol[u] = b * 7 + j;
    }
    __syncthreads();
  }

  f32x4 accH[NCT], accL[NCT];
  #pragma unroll
  for (int i = 0; i < NCT; ++i) {
    accH[i] = (f32x4){0.f, 0.f, 0.f, 0.f};
    accL[i] = (f32x4){0.f, 0.f, 0.f, 0.f};
  }

  const int r = u & 15, kg = u >> 4;
  const int c = kg >> 2;
  const int lam = (kg & 3) * 16 + r;
  const int wbyte = (c * 64 + lam) * 32;
  const int wswz = ((lam >> 2) & 1) << 4;
  const int rswz = ((lane >> 2) & 1) << 4;

  const int nph = nph1 + nph2;
  for (int ph = 0; ph < nph; ++ph) {
    // ---- load + convert 8 f32 of A (row r, k = ph*128 + kg*8) ----
    float x[8];
    if (EDGE) {
      const float* sp = Sm + (size_t)eRow[r] * 512 + ph * 128 + kg * 8;
      const float* tp = Tm + (size_t)eCol[r] * 512 + ph * 128 + kg * 8;
      float4 s0 = *(const float4*)sp, s1 = *(const float4*)(sp + 4);
      float4 t0 = *(const float4*)tp, t1 = *(const float4*)(tp + 4);
      x[0] = fmaxf(s0.x + t0.x, 0.f); x[1] = fmaxf(s0.y + t0.y, 0.f);
      x[2] = fmaxf(s0.z + t0.z, 0.f); x[3] = fmaxf(s0.w + t0.w, 0.f);
      x[4] = fmaxf(s1.x + t1.x, 0.f); x[5] = fmaxf(s1.y + t1.y, 0.f);
      x[6] = fmaxf(s1.z + t1.z, 0.f); x[7] = fmaxf(s1.w + t1.w, 0.f);
    } else {
      const float* src = (ph < nph1)
          ? X1 + (size_t)(mY + r) * ld1 + ph * 128 + kg * 8
          : X2 + (size_t)(mY + r) * ld2 + (ph - nph1) * 128 + kg * 8;
      float4 a0 = *(const float4*)src, a1 = *(const float4*)(src + 4);
      x[0] = a0.x; x[1] = a0.y; x[2] = a0.z; x[3] = a0.w;
      x[4] = a1.x; x[5] = a1.y; x[6] = a1.z; x[7] = a1.w;
    }
    f16x8 h, l;
    #pragma unroll
    for (int j = 0; j < 8; ++j) {
      _Float16 hh = (_Float16)x[j];
      h[j] = hh;
      l[j] = (_Float16)((x[j] - (float)hh) * SCL);
    }
    __syncthreads();  // prior phase's reads done
    *(f16x8*)((char*)lA + (wbyte ^ wswz)) = h;
    *(f16x8*)((char*)lA + ((wbyte + 16) ^ wswz)) = l;
    __syncthreads();
    // ---- 4 k-chunks of 32 ----
    #pragma unroll
    for (int cc = 0; cc < 4; ++cc) {
      const int cbase = (cc * 64 + lane) * 32;
      f16x8 ah = *(const f16x8*)((char*)lA + (cbase ^ rswz));
      f16x8 al = *(const f16x8*)((char*)lA + ((cbase + 16) ^ rswz));
      const int kc = ph * 4 + cc;
      const ushort_t* bp = P + (((size_t)kc * NTOT + w * NCT) * 64 + lane) * 16;
      #pragma unroll
      for (int i = 0; i < NCT; ++i) {
        f16x8 bh = *(const f16x8*)bp;
        f16x8 bl = *(const f16x8*)(bp + 8);
        bp += 64 * 16;
        accH[i] = __builtin_amdgcn_mfma_f32_16x16x32_f16(ah, bh, accH[i], 0, 0, 0);
        accL[i] = __builtin_amdgcn_mfma_f32_16x16x32_f16(ah, bl, accL[i], 0, 0, 0);
        accL[i] = __builtin_amdgcn_mfma_f32_16x16x32_f16(al, bh, accL[i], 0, 0, 0);
      }
    }
  }

  // ---- epilogue: C/D layout col = lane&15, row = (lane>>4)*4 + q ----
  const int col0 = w * NCT * 16 + (lane & 15);
  const int q0row = (lane >> 4) * 4;
  float v[NCT][4];
  #pragma unroll
  for (int i = 0; i < NCT; ++i) {
    float bc = (EPI == EP_NONE) ? 0.f : bias[col0 + i * 16];
    if (EPI == EP_AGG) bc *= 6.f;
    #pragma unroll
    for (int q = 0; q < 4; ++q)
      v[i][q] = accH[i][q] + accL[i][q] * ISCL + bc;
  }

  if (EPI == EP_NL1) {
    if (action != nullptr) {
      #pragma unroll
      for (int q = 0; q < 4; ++q) {
        int a = action[(mY + q0row + q) >> 3];
        const float* wr = wact + (size_t)(256 + a) * 512;
        #pragma unroll
        for (int i = 0; i < NCT; ++i) v[i][q] += wr[col0 + i * 16];
      }
    }
    #pragma unroll
    for (int i = 0; i < NCT; ++i)
      #pragma unroll
      for (int q = 0; q < 4; ++q) v[i][q] = fmaxf(v[i][q], 0.f);
  }

  if (EPI == EP_LN) {
    float s[4] = {0.f, 0.f, 0.f, 0.f}, sq[4] = {0.f, 0.f, 0.f, 0.f};
    #pragma unroll
    for (int i = 0; i < NCT; ++i)
      #pragma unroll
      for (int q = 0; q < 4; ++q) { s[q] += v[i][q]; sq[q] += v[i][q] * v[i][q]; }
    #pragma unroll
    for (int mm = 1; mm < 16; mm <<= 1) {
      #pragma unroll
      for (int q = 0; q < 4; ++q) {
        s[q] += __shfl_xor(s[q], mm, 64);
        sq[q] += __shfl_xor(sq[q], mm, 64);
      }
    }
    if ((lane & 15) == 0) {
      #pragma unroll
      for (int q = 0; q < 4; ++q) { redS[q0row + q][w] = s[q]; redQ[q0row + q][w] = sq[q]; }
    }
    __syncthreads();
    if (u < 16) {
      float S_ = redS[u][0] + redS[u][1] + redS[u][2] + redS[u][3];
      float Q_ = redQ[u][0] + redQ[u][1] + redQ[u][2] + redQ[u][3];
      float m_ = S_ * (1.f / N);
      float var = Q_ * (1.f / N) - m_ * m_;
      mu[u] = m_;
      rsd[u] = rsqrtf(var + 1e-5f);
    }
    __syncthreads();
    #pragma unroll
    for (int i = 0; i < NCT; ++i) {
      float gc = gg[col0 + i * 16], bnc = bnp[col0 + i * 16];
      #pragma unroll
      for (int q = 0; q < 4; ++q) {
        int row = q0row + q;
        v[i][q] = fmaxf((v[i][q] - mu[row]) * rsd[row] * gc + bnc, 0.f);
      }
    }
  }

  #pragma unroll
  for (int i = 0; i < NCT; ++i) {
    int col = col0 + i * 16;
    #pragma unroll
    for (int q = 0; q < 4; ++q) {
      int m = mY + q0row + q;
      if (EPI == EP_NL3) {
        float z = v[i][q];
        Y[(size_t)m * N + col] = z;
        Yres[(size_t)m * N + col] += z;
      } else {
        Y[(size_t)m * N + col] = v[i][q];
      }
    }
  }
}

// ---------------- sum 6 contiguous H2 rows per segment (fp32) ----------------
__global__ void h2_sum(const float* __restrict__ H2, float* __restrict__ S, int total) {
  int idx = blockIdx.x * blockDim.x + threadIdx.x;
  if (idx >= total) return;
  int cidx = idx & 511;
  int ln = idx >> 9;
  const float* p = H2 + (size_t)ln * 6 * 512 + cidx;
  S[(size_t)ln * 512 + cidx] = p[0] + p[512] + p[1024] + p[1536] + p[2048] + p[2560];
}

// ---------------- launcher ----------------
extern "C" void kernel_launch(void* const* d_in, const int* in_sizes, int n_in,
                              void* d_out, int out_size, void* d_ws, size_t ws_size,
                              hipStream_t stream) {
  (void)in_sizes; (void)n_in; (void)out_size;
  const float* states = (const float*)d_in[0];
  const int* action = (const int*)d_in[1];
  const float* e_w1 = (const float*)d_in[2];
  const float* e_b1 = (const float*)d_in[3];
  const float* e_w2 = (const float*)d_in[4];
  const float* e_b2 = (const float*)d_in[5];
  const float* e_g = (const float*)d_in[6];
  const float* e_bn = (const float*)d_in[7];
  const float* e_w3 = (const float*)d_in[8];
  const float* e_b3 = (const float*)d_in[9];
  const float* n_w1 = (const float*)d_in[10];
  const float* n_b1 = (const float*)d_in[11];
  const float* n_w2 = (const float*)d_in[12];
  const float* n_b2 = (const float*)d_in[13];
  const float* n_g = (const float*)d_in[14];
  const float* n_bn = (const float*)d_in[15];
  const float* n_w3 = (const float*)d_in[16];
  const float* n_b3 = (const float*)d_in[17];

  float* flat = (float*)d_out;                 // [8192][256]
  float* node = (float*)d_ws;                  // [8192][256]
  float* SG = node + 2097152;                  // [8192][512] agg/G/G2 (in-place chain)
  float* Sb = SG + 4194304;                    // [7168][512]
  float* Tb = Sb + 3670016;                    // [7168][512]
  ushort_t* pk = (ushort_t*)(Tb + 3670016);
  ushort_t* PeWab = pk;                        // K=512 N=512
  ushort_t* PeWc = pk + 524288;                // K=256 N=512
  ushort_t* PeW2 = pk + 786432;                // K=512 N=512
  ushort_t* PeW3 = pk + 1310720;               // K=512 N=512
  ushort_t* PnW1 = pk + 1835008;               // K=768 N=512
  ushort_t* PnW2 = pk + 2621440;               // K=512 N=512
  ushort_t* PnW3 = pk + 3145728;               // K=512 N=256
  float* H2 = (float*)(pk + 3407872);

  // choose H2 chunking to fit ws
  const size_t fixedB = 61341696ull;
  int nc = 64;
  for (int cand = 1; cand <= 64; cand <<= 1) {
    if (fixedB + 88080384ull / (size_t)cand <= ws_size) { nc = cand; break; }
  }
  const int spc = 1024 / nc;   // samples per chunk
  const int epc = spc * 42;    // edges per chunk

  // prepack weights (hi/lo f16, fragment-native)
  prepack<<<1024, 256, 0, stream>>>(e_w1, PeWab, 0, 512, 512, 32);
  prepack<<<512, 256, 0, stream>>>(e_w1 + 262144, PeWc, 0, 256, 512, 32);
  prepack<<<1024, 256, 0, stream>>>(e_w2, PeW2, 0, 512, 512, 32);
  prepack<<<1024, 256, 0, stream>>>(e_w3, PeW3, 0, 512, 512, 32);
  prepack<<<512, 256, 0, stream>>>(n_w1, PnW1, 0, 256, 512, 32);
  prepack<<<1024, 256, 0, stream>>>(n_w1 + 133120, PnW1, 256, 512, 512, 32);
  prepack<<<1024, 256, 0, stream>>>(n_w2, PnW2, 0, 512, 512, 32);
  prepack<<<512, 256, 0, stream>>>(n_w3, PnW3, 0, 512, 256, 16);

  hipMemcpyAsync(flat, states, (size_t)NNODE * 256 * 4, hipMemcpyDeviceToDevice, stream);

  for (int round = 0; round < 8; ++round) {
    // S = flat7@Wa (+ node7@Wb) + b1 ; T = flat7@Wc
    if (round == 0)
      gemm16<32, 8, EP_BIAS, 0><<<448, 256, 0, stream>>>(
          flat, 256, 2, nullptr, 0, 0, nullptr, nullptr, PeWab, e_b1,
          nullptr, nullptr, nullptr, nullptr, Sb, nullptr, 0);
    else
      gemm16<32, 8, EP_BIAS, 0><<<448, 256, 0, stream>>>(
          flat, 256, 2, node, 256, 2, nullptr, nullptr, PeWab, e_b1,
          nullptr, nullptr, nullptr, nullptr, Sb, nullptr, 0);
    gemm16<32, 8, EP_NONE, 0><<<448, 256, 0, stream>>>(
        flat, 256, 2, nullptr, 0, 0, nullptr, nullptr, PeWc, nullptr,
        nullptr, nullptr, nullptr, nullptr, Tb, nullptr, 0);
    // edge layer 2 (+LN) fused with gather/relu of S[row]+T[col]; then 6-row sums
    for (int ch = 0; ch < nc; ++ch) {
      gemm16<32, 8, EP_LN, 1><<<epc / 16, 256, 0, stream>>>(
          nullptr, 0, 4, nullptr, 0, 0, Sb, Tb, PeW2, e_b2,
          e_g, e_bn, nullptr, nullptr, H2, nullptr, ch * epc);
      h2_sum<<<(spc * 3584 + 255) / 256, 256, 0, stream>>>(
          H2, SG + (size_t)ch * spc * 7 * 512, spc * 3584);
    }
    // agg = SS@e_w3 + 6*b3 (rows<7168), zeros elsewhere — in-place on SG
    gemm16<32, 8, EP_AGG, 0><<<512, 256, 0, stream>>>(
        SG, 512, 4, nullptr, 0, 0, nullptr, nullptr, PeW3, e_b3,
        nullptr, nullptr, nullptr, nullptr, SG, nullptr, 0);
    // node layer 1: relu(flat@W1f + av@W1av + agg@W1g + b1) — in-place on SG
    gemm16<32, 8, EP_NL1, 0><<<512, 256, 0, stream>>>(
        flat, 256, 2, SG, 512, 4, nullptr, nullptr, PnW1, n_b1,
        nullptr, nullptr, (round == 0) ? action : nullptr, n_w1, SG, nullptr, 0);
    // node layer 2 (+LN) — in-place on SG
    gemm16<32, 8, EP_LN, 0><<<512, 256, 0, stream>>>(
        SG, 512, 4, nullptr, 0, 0, nullptr, nullptr, PnW2, n_b2,
        n_g, n_bn, nullptr, nullptr, SG, nullptr, 0);
    // node layer 3 + residual
    gemm16<16, 4, EP_NL3, 0><<<512, 256, 0, stream>>>(
        SG, 512, 4, nullptr, 0, 0, nullptr, nullptr, PnW3, n_b3,
        nullptr, nullptr, nullptr, nullptr, node, flat, 0);
  }
}

// Round 4
// 2324.368 us; speedup vs baseline: 4.8272x; 1.4248x over previous
//
#include <hip/hip_runtime.h>
#include <cstddef>

typedef _Float16 f16x8 __attribute__((ext_vector_type(8)));
typedef float f32x16 __attribute__((ext_vector_type(16)));
typedef float f32x4 __attribute__((ext_vector_type(4)));
typedef unsigned short ushort_t;

#define SCL 4096.f
#define ISCL (1.f / 4096.f)
#define NSEG 7168
#define NNODE 8192

enum { EP_NONE = 0, EP_BIAS = 1, EP_RAWP = 2, EP_AGG = 3, EP_NL1 = 4, EP_NL3 = 5 };

// ---- prepack W[k][n] fp32 -> 32x32-fragment-native f16 hi/lo -------------
// P[((kc*NT + nt)*64 + lane)*16 + j] : lane = ((k>>3)&1)*32 + (n&31), j = k&7
__global__ __launch_bounds__(256)
void prepack(const float* __restrict__ W, ushort_t* __restrict__ P,
             int koff, int kcnt, int N) {
  int idx = blockIdx.x * 256 + threadIdx.x;
  if (idx >= kcnt * N) return;
  int kl = idx / N, n = idx - kl * N;
  float wv = W[idx];
  _Float16 h = (_Float16)wv;
  _Float16 l = (_Float16)((wv - (float)h) * SCL);
  int k = koff + kl;
  int NT = N >> 5;
  size_t o = ((((size_t)(k >> 4)) * NT + (n >> 5)) * 64 + ((k >> 3) & 1) * 32 + (n & 31)) * 16 + (k & 7);
  P[o] = __builtin_bit_cast(ushort_t, h);
  P[o + 8] = __builtin_bit_cast(ushort_t, l);
}

// ---- unified 64x128-tile MFMA GEMM (split-f16, 32x32x16) -----------------
template <int NCOLB, int EPI, int EDGE, int LNIN>
__global__ __launch_bounds__(256, 2)
void gemmT(const float* __restrict__ X1, int ld1, int nph1,
           const float* __restrict__ X2, int ld2, int nph2,
           const float* __restrict__ Sm, const float* __restrict__ Tm,
           const ushort_t* __restrict__ P,
           const float* __restrict__ bias,
           const int* __restrict__ action, const float* __restrict__ wact,
           const float* __restrict__ lnmu, const float* __restrict__ lnrsd,
           const float* __restrict__ lng, const float* __restrict__ lnbn,
           float* __restrict__ Y, float* __restrict__ Yres,
           float* __restrict__ Part, int m0base) {
  constexpr int N = NCOLB * 128;
  constexpr int NT = N / 32;
  const int u = threadIdx.x;
  const int mY = blockIdx.x * 64;
  const int nB = blockIdx.y * 128;

  if (EPI == EP_AGG && mY >= NSEG) {
    #pragma unroll
    for (int i = 0; i < 8; ++i) {
      int li = u + 256 * i;
      int row = li >> 5, cs = li & 31;
      *(f32x4*)(Y + (size_t)(mY + row) * N + nB + cs * 4) = (f32x4){0.f, 0.f, 0.f, 0.f};
    }
    return;
  }

  const int lane = u & 63, w = u >> 6, wr = w >> 1, wc = w & 1;
  __shared__ ushort_t lA[8192];           // [rt2][ks4][khi2][rr32][8] hi | +4096 lo
  __shared__ int eR[64], eC[64];

  if (EDGE) {
    if (u < 64) {
      int e = m0base + mY + u;
      int b = e / 42, p = e - b * 42;
      int i = p / 6, tt = p - i * 6;
      int j = tt + (tt >= i ? 1 : 0);
      eR[u] = b * 7 + i;
      eC[u] = b * 7 + j;
    }
    __syncthreads();
  }

  const int srow = u >> 2, skq = u & 3;
  const int srt = srow >> 5, srr = srow & 31;
  const int gofs0 = (((srt * 4 + skq) * 2 + 0) * 32 + (srr ^ (skq << 3))) * 8;
  const int gofs1 = gofs0 + 256;

  const float* sB = nullptr;
  const float* tB = nullptr;
  const float* x1B = nullptr;
  const float* x2B = nullptr;
  if (EDGE) {
    sB = Sm + (size_t)eR[srow] * 512 + skq * 16;
    tB = Tm + (size_t)eC[srow] * 512 + skq * 16;
  } else {
    x1B = X1 + (size_t)(mY + srow) * ld1 + skq * 16;
    if (nph2 > 0) x2B = X2 + (size_t)(mY + srow) * ld2 + skq * 16;
  }
  float mym = 0.f, myr = 0.f;
  if (LNIN) { mym = lnmu[mY + srow]; myr = lnrsd[mY + srow]; }

  auto loadx = [&](int ph, float* x) {
    if (EDGE) {
      const float* sp = sB + ph * 64;
      const float* tp = tB + ph * 64;
      #pragma unroll
      for (int q4 = 0; q4 < 4; ++q4) {
        float4 sv = *(const float4*)(sp + q4 * 4);
        float4 tv = *(const float4*)(tp + q4 * 4);
        x[q4 * 4 + 0] = fmaxf(sv.x + tv.x, 0.f);
        x[q4 * 4 + 1] = fmaxf(sv.y + tv.y, 0.f);
        x[q4 * 4 + 2] = fmaxf(sv.z + tv.z, 0.f);
        x[q4 * 4 + 3] = fmaxf(sv.w + tv.w, 0.f);
      }
    } else {
      const float* src = (ph < nph1) ? x1B + ph * 64 : x2B + (ph - nph1) * 64;
      #pragma unroll
      for (int q4 = 0; q4 < 4; ++q4)
        *(float4*)&x[q4 * 4] = *(const float4*)(src + q4 * 4);
      if (LNIN) {
        int kb = ph * 64 + skq * 16;
        #pragma unroll
        for (int q4 = 0; q4 < 4; ++q4) {
          float4 gv = *(const float4*)(lng + kb + q4 * 4);
          float4 bv = *(const float4*)(lnbn + kb + q4 * 4);
          x[q4 * 4 + 0] = fmaxf((x[q4 * 4 + 0] - mym) * myr * gv.x + bv.x, 0.f);
          x[q4 * 4 + 1] = fmaxf((x[q4 * 4 + 1] - mym) * myr * gv.y + bv.y, 0.f);
          x[q4 * 4 + 2] = fmaxf((x[q4 * 4 + 2] - mym) * myr * gv.z + bv.z, 0.f);
          x[q4 * 4 + 3] = fmaxf((x[q4 * 4 + 3] - mym) * myr * gv.w + bv.w, 0.f);
        }
      }
    }
  };

  f32x16 accH[2], accL[2];
  #pragma unroll
  for (int ct = 0; ct < 2; ++ct)
    #pragma unroll
    for (int q = 0; q < 16; ++q) { accH[ct][q] = 0.f; accL[ct][q] = 0.f; }

  const int nph = nph1 + nph2;
  const int ntb = (nB >> 5) + wc * 2;

  float xc[16];
  loadx(0, xc);

  #pragma unroll 1
  for (int ph = 0; ph < nph; ++ph) {
    f16x8 h0, h1, l0, l1;
    #pragma unroll
    for (int j = 0; j < 8; ++j) {
      float a = xc[j], b2 = xc[8 + j];
      _Float16 ha = (_Float16)a, hb = (_Float16)b2;
      h0[j] = ha; l0[j] = (_Float16)((a - (float)ha) * SCL);
      h1[j] = hb; l1[j] = (_Float16)((b2 - (float)hb) * SCL);
    }
    __syncthreads();
    *(f16x8*)&lA[gofs0] = h0;
    *(f16x8*)&lA[gofs0 + 4096] = l0;
    *(f16x8*)&lA[gofs1] = h1;
    *(f16x8*)&lA[gofs1 + 4096] = l1;
    __syncthreads();
    if (ph + 1 < nph) loadx(ph + 1, xc);   // overlap next-step loads with MFMA
    #pragma unroll
    for (int s = 0; s < 4; ++s) {
      const int aofs = (((wr * 4 + s) * 2 + (lane >> 5)) * 32 + ((lane & 31) ^ (s << 3))) * 8;
      f16x8 ah = *(const f16x8*)&lA[aofs];
      f16x8 al = *(const f16x8*)&lA[aofs + 4096];
      const ushort_t* bp = P + (((size_t)(ph * 4 + s) * NT + ntb) * 64 + lane) * 16;
      #pragma unroll
      for (int ct = 0; ct < 2; ++ct) {
        f16x8 bh = *(const f16x8*)bp;
        f16x8 bl = *(const f16x8*)(bp + 8);
        accH[ct] = __builtin_amdgcn_mfma_f32_32x32x16_f16(ah, bh, accH[ct], 0, 0, 0);
        accL[ct] = __builtin_amdgcn_mfma_f32_32x32x16_f16(ah, bl, accL[ct], 0, 0, 0);
        accL[ct] = __builtin_amdgcn_mfma_f32_32x32x16_f16(al, bh, accL[ct], 0, 0, 0);
        bp += 64 * 16;
      }
    }
  }

  // ---- epilogue: C/D col = lane&31, row = (q&3) + 8*(q>>2) + 4*(lane>>5) --
  const int col0 = nB + wc * 64 + (lane & 31);
  float v[2][16];
  #pragma unroll
  for (int ct = 0; ct < 2; ++ct) {
    float bc = 0.f;
    if (EPI != EP_NONE) {
      bc = bias[col0 + ct * 32];
      if (EPI == EP_AGG) bc *= 6.f;
    }
    #pragma unroll
    for (int q = 0; q < 16; ++q)
      v[ct][q] = accH[ct][q] + accL[ct][q] * ISCL + bc;
  }

  if (EPI == EP_NL1) {
    if (action != nullptr) {
      #pragma unroll
      for (int q = 0; q < 16; ++q) {
        int m = mY + wr * 32 + (q & 3) + 8 * (q >> 2) + 4 * (lane >> 5);
        const float* wrp = wact + (size_t)(256 + action[m >> 3]) * 512;
        v[0][q] += wrp[col0];
        v[1][q] += wrp[col0 + 32];
      }
    }
    #pragma unroll
    for (int ct = 0; ct < 2; ++ct)
      #pragma unroll
      for (int q = 0; q < 16; ++q) v[ct][q] = fmaxf(v[ct][q], 0.f);
  }

  if (EPI == EP_RAWP) {
    float sv[16], qv[16];
    #pragma unroll
    for (int q = 0; q < 16; ++q) {
      sv[q] = v[0][q] + v[1][q];
      qv[q] = v[0][q] * v[0][q] + v[1][q] * v[1][q];
    }
    #pragma unroll
    for (int mm = 1; mm <= 16; mm <<= 1) {
      #pragma unroll
      for (int q = 0; q < 16; ++q) {
        sv[q] += __shfl_xor(sv[q], mm);
        qv[q] += __shfl_xor(qv[q], mm);
      }
    }
    if ((lane & 31) == 0) {
      #pragma unroll
      for (int q = 0; q < 16; ++q) {
        int m = mY + wr * 32 + (q & 3) + 8 * (q >> 2) + 4 * (lane >> 5);
        Part[(size_t)m * 16 + blockIdx.y * 2 + wc] = sv[q];
        Part[(size_t)m * 16 + 8 + blockIdx.y * 2 + wc] = qv[q];
      }
    }
  }

  #pragma unroll
  for (int ct = 0; ct < 2; ++ct) {
    #pragma unroll
    for (int q = 0; q < 16; ++q) {
      int m = mY + wr * 32 + (q & 3) + 8 * (q >> 2) + 4 * (lane >> 5);
      float z = v[ct][q];
      Y[(size_t)m * N + col0 + ct * 32] = z;
      if (EPI == EP_NL3) Yres[(size_t)m * N + col0 + ct * 32] += z;
    }
  }
}

// ---- per-row LN stats from 8 column-block partials -----------------------
__global__ __launch_bounds__(256)
void rowstats(const float* __restrict__ Part, float* __restrict__ mu,
              float* __restrict__ rsd, int M) {
  int m = blockIdx.x * 256 + threadIdx.x;
  if (m >= M) return;
  const float* p = Part + (size_t)m * 16;
  float S = 0.f, Q = 0.f;
  #pragma unroll
  for (int i = 0; i < 8; ++i) { S += p[i]; Q += p[8 + i]; }
  float mm = S * (1.f / 512.f);
  mu[m] = mm;
  rsd[m] = rsqrtf(Q * (1.f / 512.f) - mm * mm + 1e-5f);
}

// ---- apply LN+relu to 6 H2 rows and sum per segment ----------------------
__global__ __launch_bounds__(256)
void h2_sum_ln(const float* __restrict__ H2, const float* __restrict__ mu,
               const float* __restrict__ rsd, const float* __restrict__ g,
               const float* __restrict__ bn, float* __restrict__ SS, int nrows) {
  int id = blockIdx.x * 256 + threadIdx.x;
  if (id >= nrows * 128) return;
  int ln = id >> 7, c4 = (id & 127) * 4;
  float4 gv = *(const float4*)(g + c4);
  float4 bv = *(const float4*)(bn + c4);
  float ax = 0.f, ay = 0.f, az = 0.f, aw = 0.f;
  #pragma unroll
  for (int r = 0; r < 6; ++r) {
    int row = ln * 6 + r;
    float4 y = *(const float4*)(H2 + (size_t)row * 512 + c4);
    float m = mu[row], rs = rsd[row];
    ax += fmaxf((y.x - m) * rs * gv.x + bv.x, 0.f);
    ay += fmaxf((y.y - m) * rs * gv.y + bv.y, 0.f);
    az += fmaxf((y.z - m) * rs * gv.z + bv.z, 0.f);
    aw += fmaxf((y.w - m) * rs * gv.w + bv.w, 0.f);
  }
  float4 o; o.x = ax; o.y = ay; o.z = az; o.w = aw;
  *(float4*)(SS + (size_t)ln * 512 + c4) = o;
}

// ---- launcher ------------------------------------------------------------
extern "C" void kernel_launch(void* const* d_in, const int* in_sizes, int n_in,
                              void* d_out, int out_size, void* d_ws, size_t ws_size,
                              hipStream_t stream) {
  (void)in_sizes; (void)n_in; (void)out_size;
  const float* states = (const float*)d_in[0];
  const int* action = (const int*)d_in[1];
  const float* e_w1 = (const float*)d_in[2];
  const float* e_b1 = (const float*)d_in[3];
  const float* e_w2 = (const float*)d_in[4];
  const float* e_b2 = (const float*)d_in[5];
  const float* e_g = (const float*)d_in[6];
  const float* e_bn = (const float*)d_in[7];
  const float* e_w3 = (const float*)d_in[8];
  const float* e_b3 = (const float*)d_in[9];
  const float* n_w1 = (const float*)d_in[10];
  const float* n_b1 = (const float*)d_in[11];
  const float* n_w2 = (const float*)d_in[12];
  const float* n_b2 = (const float*)d_in[13];
  const float* n_g = (const float*)d_in[14];
  const float* n_bn = (const float*)d_in[15];
  const float* n_w3 = (const float*)d_in[16];
  const float* n_b3 = (const float*)d_in[17];

  float* flat = (float*)d_out;                  // [8192][256]
  float* node = (float*)d_ws;                   // [8192][256]
  float* bufA = node + 2097152;                 // [8192][512]
  float* bufB = bufA + 4194304;                 // [8192][512]
  float* Sb = bufB + 4194304;                   // [7168][512]
  float* Tb = Sb + 3670016;                     // [7168][512]
  ushort_t* pk = (ushort_t*)(Tb + 3670016);
  ushort_t* PeWab = pk;                         // K512 N512
  ushort_t* PeWc = pk + 524288;                 // K256 N512
  ushort_t* PeW2 = pk + 786432;                 // K512 N512
  ushort_t* PeW3 = pk + 1310720;                // K512 N512
  ushort_t* PnW1 = pk + 1835008;                // K768 N512
  ushort_t* PnW2 = pk + 2621440;                // K512 N512
  ushort_t* PnW3 = pk + 3145728;                // K512 N256
  float* fb = (float*)(pk + 3407872);
  float* muE = fb;                              // 43008
  float* rsdE = muE + 43008;
  float* muN = rsdE + 43008;                    // 8192
  float* rsdN = muN + 8192;
  float* PartE = rsdN + 8192;                   // 43008*16
  float* PartN = PartE + 688128;                // 8192*16
  float* H2raw = PartN + 131072;

  const size_t fixedB = (size_t)((char*)H2raw - (char*)d_ws);
  int nc = 32;
  for (int cand = 1; cand <= 32; cand <<= 1)
    if (fixedB + (43008ull / cand) * 512ull * 4ull <= ws_size) { nc = cand; break; }
  const int spc = 1024 / nc;
  const int epc = spc * 42;

  prepack<<<1024, 256, 0, stream>>>(e_w1, PeWab, 0, 512, 512);
  prepack<<<512, 256, 0, stream>>>(e_w1 + 262144, PeWc, 0, 256, 512);
  prepack<<<1024, 256, 0, stream>>>(e_w2, PeW2, 0, 512, 512);
  prepack<<<1024, 256, 0, stream>>>(e_w3, PeW3, 0, 512, 512);
  prepack<<<512, 256, 0, stream>>>(n_w1, PnW1, 0, 256, 512);
  prepack<<<1024, 256, 0, stream>>>(n_w1 + 133120, PnW1, 256, 512, 512);
  prepack<<<1024, 256, 0, stream>>>(n_w2, PnW2, 0, 512, 512);
  prepack<<<512, 256, 0, stream>>>(n_w3, PnW3, 0, 512, 256);

  hipMemcpyAsync(flat, states, (size_t)NNODE * 256 * 4, hipMemcpyDeviceToDevice, stream);

  for (int round = 0; round < 8; ++round) {
    // S = flat7@Wa (+ node7@Wb) + b1 ; T = flat7@Wc   (7168 rows -> 112 blocks of 64)
    if (round == 0)
      gemmT<4, EP_BIAS, 0, 0><<<dim3(112, 4), 256, 0, stream>>>(
          flat, 256, 4, nullptr, 0, 0, nullptr, nullptr, PeWab, e_b1,
          nullptr, nullptr, nullptr, nullptr, nullptr, nullptr, Sb, nullptr, nullptr, 0);
    else
      gemmT<4, EP_BIAS, 0, 0><<<dim3(112, 4), 256, 0, stream>>>(
          flat, 256, 4, node, 256, 4, nullptr, nullptr, PeWab, e_b1,
          nullptr, nullptr, nullptr, nullptr, nullptr, nullptr, Sb, nullptr, nullptr, 0);
    gemmT<4, EP_NONE, 0, 0><<<dim3(112, 4), 256, 0, stream>>>(
        flat, 256, 4, nullptr, 0, 0, nullptr, nullptr, PeWc, nullptr,
        nullptr, nullptr, nullptr, nullptr, nullptr, nullptr, Tb, nullptr, nullptr, 0);
    // edge layer 2 raw + partials; stats; LN+relu+sum6
    for (int ch = 0; ch < nc; ++ch) {
      gemmT<4, EP_RAWP, 1, 0><<<dim3(epc / 64, 4), 256, 0, stream>>>(
          nullptr, 0, 8, nullptr, 0, 0, Sb, Tb, PeW2, e_b2,
          nullptr, nullptr, nullptr, nullptr, nullptr, nullptr,
          H2raw, nullptr, PartE, ch * epc);
      rowstats<<<(epc + 255) / 256, 256, 0, stream>>>(PartE, muE, rsdE, epc);
      h2_sum_ln<<<(spc * 7 * 128) / 256, 256, 0, stream>>>(
          H2raw, muE, rsdE, e_g, e_bn, bufA + (size_t)ch * spc * 7 * 512, spc * 7);
    }
    // agg = SS@e_w3 + 6*b3 (rows<7168), zeros elsewhere: bufA -> bufB
    gemmT<4, EP_AGG, 0, 0><<<dim3(128, 4), 256, 0, stream>>>(
        bufA, 512, 8, nullptr, 0, 0, nullptr, nullptr, PeW3, e_b3,
        nullptr, nullptr, nullptr, nullptr, nullptr, nullptr, bufB, nullptr, nullptr, 0);
    // node L1: relu(flat@W1f + av@W1av + agg@W1g + b1): bufB -> bufA
    gemmT<4, EP_NL1, 0, 0><<<dim3(128, 4), 256, 0, stream>>>(
        flat, 256, 4, bufB, 512, 8, nullptr, nullptr, PnW1, n_b1,
        (round == 0) ? action : nullptr, n_w1,
        nullptr, nullptr, nullptr, nullptr, bufA, nullptr, nullptr, 0);
    // node L2 raw + partials: bufA -> bufB; stats
    gemmT<4, EP_RAWP, 0, 0><<<dim3(128, 4), 256, 0, stream>>>(
        bufA, 512, 8, nullptr, 0, 0, nullptr, nullptr, PnW2, n_b2,
        nullptr, nullptr, nullptr, nullptr, nullptr, nullptr, bufB, nullptr, PartN, 0);
    rowstats<<<32, 256, 0, stream>>>(PartN, muN, rsdN, 8192);
    // node L3 (+LN-on-staging) + residual: bufB -> node, flat+=
    gemmT<2, EP_NL3, 0, 1><<<dim3(128, 2), 256, 0, stream>>>(
        bufB, 512, 8, nullptr, 0, 0, nullptr, nullptr, PnW3, n_b3,
        nullptr, nullptr, muN, rsdN, n_g, n_bn, node, flat, nullptr, 0);
  }
}

// Round 5
// 2089.670 us; speedup vs baseline: 5.3694x; 1.1123x over previous
//
#include <hip/hip_runtime.h>
#include <cstddef>

typedef _Float16 f16x8 __attribute__((ext_vector_type(8)));
typedef float f32x16 __attribute__((ext_vector_type(16)));
typedef float f32x4 __attribute__((ext_vector_type(4)));
typedef unsigned short ushort_t;

#define SCL 4096.f
#define ISCL (1.f / 4096.f)
#define NSEG 7168
#define NNODE 8192

enum { EP_NONE = 0, EP_BIAS = 1, EP_RAWP = 2, EP_NL1 = 3, EP_NL3 = 4 };

#define PHASE_BARRIER() do { asm volatile("s_waitcnt lgkmcnt(0)" ::: "memory"); \
                             __builtin_amdgcn_s_barrier(); } while (0)

// ---- prepack W[k][n] fp32 -> 32x32-fragment-native f16 hi/lo -------------
// P[((kc*NT + nt)*64 + lane)*16 + j] : lane = ((k>>3)&1)*32 + (n&31), j = k&7
__global__ __launch_bounds__(256)
void prepack(const float* __restrict__ W, ushort_t* __restrict__ P,
             int koff, int kcnt, int N) {
  int idx = blockIdx.x * 256 + threadIdx.x;
  if (idx >= kcnt * N) return;
  int kl = idx / N, n = idx - kl * N;
  float wv = W[idx];
  _Float16 h = (_Float16)wv;
  _Float16 l = (_Float16)((wv - (float)h) * SCL);
  int k = koff + kl;
  int NT = N >> 5;
  size_t o = ((((size_t)(k >> 4)) * NT + (n >> 5)) * 64 + ((k >> 3) & 1) * 32 + (n & 31)) * 16 + (k & 7);
  P[o] = __builtin_bit_cast(ushort_t, h);
  P[o + 8] = __builtin_bit_cast(ushort_t, l);
}

// ---- v6[n] = 6 * sum_k e_b3[k] * n_w1[260+k][n] --------------------------
__global__ __launch_bounds__(256)
void v6k(const float* __restrict__ eb3, const float* __restrict__ nw1,
         float* __restrict__ v6) {
  int n = blockIdx.x * 256 + threadIdx.x;
  if (n >= 512) return;
  float a = 0.f;
  for (int k = 0; k < 512; ++k) a += eb3[k] * nw1[(size_t)(260 + k) * 512 + n];
  v6[n] = 6.f * a;
}

// ---- unified 64x128-tile MFMA GEMM (split-f16, 32x32x16), pipelined ------
template <int NCOLB, int EPI, int EDGE, int LNIN>
__global__ __launch_bounds__(256, 2)
void gemmT(const float* __restrict__ X1, int ld1, int nph1,
           const float* __restrict__ X2, int ld2, int nph2,
           const float* __restrict__ Sm, const float* __restrict__ Tm,
           const ushort_t* __restrict__ P,
           const float* __restrict__ bias, const float* __restrict__ bias2,
           const int* __restrict__ action, const float* __restrict__ wact,
           const float* __restrict__ lnmu, const float* __restrict__ lnrsd,
           const float* __restrict__ lng, const float* __restrict__ lnbn,
           float* __restrict__ Y, float* __restrict__ Yres,
           float* __restrict__ Part, int m0base) {
  constexpr int N = NCOLB * 128;
  constexpr int NT = N / 32;
  const int u = threadIdx.x;
  const int mY = blockIdx.x * 64;
  const int nB = blockIdx.y * 128;
  const int lane = u & 63, w = u >> 6, wr = w >> 1, wc = w & 1;

  __shared__ ushort_t lA[16384];          // 2 x (4096 hi + 4096 lo) ushorts
  __shared__ int eR[64], eC[64];

  if (EDGE) {
    if (u < 64) {
      int e = m0base + mY + u;
      int b = e / 42, p = e - b * 42;
      int i = p / 6, tt = p - i * 6;
      int j = tt + (tt >= i ? 1 : 0);
      eR[u] = b * 7 + i;
      eC[u] = b * 7 + j;
    }
    __syncthreads();
  }

  const int srow = u >> 2, skq = u & 3;
  const int srt = srow >> 5, srr = srow & 31;
  const int gofs0 = (((srt * 4 + skq) * 2 + 0) * 32 + (srr ^ (skq << 3))) * 8;
  const int gofs1 = gofs0 + 256;

  const float* sB = nullptr;
  const float* tB = nullptr;
  const float* x1B = nullptr;
  const float* x2B = nullptr;
  if (EDGE) {
    sB = Sm + (size_t)eR[srow] * 512 + skq * 16;
    tB = Tm + (size_t)eC[srow] * 512 + skq * 16;
  } else {
    x1B = X1 + (size_t)(mY + srow) * ld1 + skq * 16;
    if (nph2 > 0) x2B = X2 + (size_t)(mY + srow) * ld2 + skq * 16;
  }
  float mym = 0.f, myr = 0.f;
  if (LNIN) { mym = lnmu[mY + srow]; myr = lnrsd[mY + srow]; }

  float xc[16];
  auto loadx = [&](int ph) {
    if (EDGE) {
      const float* sp = sB + ph * 64;
      const float* tp = tB + ph * 64;
      #pragma unroll
      for (int q4 = 0; q4 < 4; ++q4) {
        float4 sv = *(const float4*)(sp + q4 * 4);
        float4 tv = *(const float4*)(tp + q4 * 4);
        xc[q4 * 4 + 0] = fmaxf(sv.x + tv.x, 0.f);
        xc[q4 * 4 + 1] = fmaxf(sv.y + tv.y, 0.f);
        xc[q4 * 4 + 2] = fmaxf(sv.z + tv.z, 0.f);
        xc[q4 * 4 + 3] = fmaxf(sv.w + tv.w, 0.f);
      }
    } else {
      const float* src = (ph < nph1) ? x1B + ph * 64 : x2B + (ph - nph1) * 64;
      #pragma unroll
      for (int q4 = 0; q4 < 4; ++q4)
        *(float4*)&xc[q4 * 4] = *(const float4*)(src + q4 * 4);
      if (LNIN) {
        int kb = ph * 64 + skq * 16;
        #pragma unroll
        for (int q4 = 0; q4 < 4; ++q4) {
          float4 gv = *(const float4*)(lng + kb + q4 * 4);
          float4 bv = *(const float4*)(lnbn + kb + q4 * 4);
          xc[q4 * 4 + 0] = fmaxf((xc[q4 * 4 + 0] - mym) * myr * gv.x + bv.x, 0.f);
          xc[q4 * 4 + 1] = fmaxf((xc[q4 * 4 + 1] - mym) * myr * gv.y + bv.y, 0.f);
          xc[q4 * 4 + 2] = fmaxf((xc[q4 * 4 + 2] - mym) * myr * gv.z + bv.z, 0.f);
          xc[q4 * 4 + 3] = fmaxf((xc[q4 * 4 + 3] - mym) * myr * gv.w + bv.w, 0.f);
        }
      }
    }
  };
  auto cvtwrite = [&](int b) {
    f16x8 h0, h1, l0, l1;
    #pragma unroll
    for (int j = 0; j < 8; ++j) {
      float a = xc[j], b2 = xc[8 + j];
      _Float16 ha = (_Float16)a, hb = (_Float16)b2;
      h0[j] = ha; l0[j] = (_Float16)((a - (float)ha) * SCL);
      h1[j] = hb; l1[j] = (_Float16)((b2 - (float)hb) * SCL);
    }
    const int base = b * 8192;
    *(f16x8*)&lA[base + gofs0] = h0;
    *(f16x8*)&lA[base + gofs0 + 4096] = l0;
    *(f16x8*)&lA[base + gofs1] = h1;
    *(f16x8*)&lA[base + gofs1 + 4096] = l1;
  };

  f32x16 accH[2], accL[2];
  #pragma unroll
  for (int ct = 0; ct < 2; ++ct)
    #pragma unroll
    for (int q = 0; q < 16; ++q) { accH[ct][q] = 0.f; accL[ct][q] = 0.f; }

  const int nph = nph1 + nph2;
  const int ntb = (nB >> 5) + wc * 2;

  // prologue: stage phase 0, issue phase-1 loads, prefetch B(0)
  loadx(0);
  cvtwrite(0);
  if (nph > 1) loadx(1);
  PHASE_BARRIER();
  f16x8 bhP0, blP0, bhP1, blP1;
  {
    const ushort_t* bp_ = P + ((size_t)ntb * 64 + lane) * 16;
    bhP0 = *(const f16x8*)bp_;          blP0 = *(const f16x8*)(bp_ + 8);
    bhP1 = *(const f16x8*)(bp_ + 1024); blP1 = *(const f16x8*)(bp_ + 1032);
  }

  #pragma unroll 1
  for (int ph = 0; ph < nph; ++ph) {
    if (ph + 1 < nph) {
      cvtwrite((ph + 1) & 1);          // stage next phase into other buffer
      if (ph + 2 < nph) loadx(ph + 2); // issue next-next global loads
    }
    const int lbase = (ph & 1) * 8192;
    #pragma unroll
    for (int s = 0; s < 4; ++s) {
      const int aofs = lbase + (((wr * 4 + s) * 2 + (lane >> 5)) * 32 + ((lane & 31) ^ (s << 3))) * 8;
      f16x8 ah = *(const f16x8*)&lA[aofs];
      f16x8 al = *(const f16x8*)&lA[aofs + 4096];
      f16x8 b0h = bhP0, b0l = blP0, b1h = bhP1, b1l = blP1;
      const int kcn = ph * 4 + s + 1;
      if (kcn < nph * 4) {             // prefetch next B fragments
        const ushort_t* bp_ = P + (((size_t)kcn * NT + ntb) * 64 + lane) * 16;
        bhP0 = *(const f16x8*)bp_;          blP0 = *(const f16x8*)(bp_ + 8);
        bhP1 = *(const f16x8*)(bp_ + 1024); blP1 = *(const f16x8*)(bp_ + 1032);
      }
      accH[0] = __builtin_amdgcn_mfma_f32_32x32x16_f16(ah, b0h, accH[0], 0, 0, 0);
      accL[0] = __builtin_amdgcn_mfma_f32_32x32x16_f16(ah, b0l, accL[0], 0, 0, 0);
      accL[0] = __builtin_amdgcn_mfma_f32_32x32x16_f16(al, b0h, accL[0], 0, 0, 0);
      accH[1] = __builtin_amdgcn_mfma_f32_32x32x16_f16(ah, b1h, accH[1], 0, 0, 0);
      accL[1] = __builtin_amdgcn_mfma_f32_32x32x16_f16(ah, b1l, accL[1], 0, 0, 0);
      accL[1] = __builtin_amdgcn_mfma_f32_32x32x16_f16(al, b1h, accL[1], 0, 0, 0);
    }
    if (ph + 1 < nph) PHASE_BARRIER();
  }

  // ---- epilogue: C/D col = lane&31, row = (q&3) + 8*(q>>2) + 4*(lane>>5) --
  const int col0 = nB + wc * 64 + (lane & 31);
  float v[2][16];
  #pragma unroll
  for (int ct = 0; ct < 2; ++ct) {
    float bc = (EPI == EP_NONE) ? 0.f : bias[col0 + ct * 32];
    #pragma unroll
    for (int q = 0; q < 16; ++q)
      v[ct][q] = accH[ct][q] + accL[ct][q] * ISCL + bc;
  }

  if (EPI == EP_NL1) {
    #pragma unroll
    for (int q = 0; q < 16; ++q) {
      int m = mY + wr * 32 + (q & 3) + 8 * (q >> 2) + 4 * (lane >> 5);
      if (m < NSEG) {                  // agg-derived bias only where edges exist
        v[0][q] += bias2[col0];
        v[1][q] += bias2[col0 + 32];
      }
      if (action != nullptr) {
        const float* wrp = wact + (size_t)(256 + action[m >> 3]) * 512;
        v[0][q] += wrp[col0];
        v[1][q] += wrp[col0 + 32];
      }
    }
    #pragma unroll
    for (int ct = 0; ct < 2; ++ct)
      #pragma unroll
      for (int q = 0; q < 16; ++q) v[ct][q] = fmaxf(v[ct][q], 0.f);
  }

  if (EPI == EP_RAWP) {
    float sv[16], qv[16];
    #pragma unroll
    for (int q = 0; q < 16; ++q) {
      sv[q] = v[0][q] + v[1][q];
      qv[q] = v[0][q] * v[0][q] + v[1][q] * v[1][q];
    }
    #pragma unroll
    for (int mm = 1; mm <= 16; mm <<= 1) {
      #pragma unroll
      for (int q = 0; q < 16; ++q) {
        sv[q] += __shfl_xor(sv[q], mm);
        qv[q] += __shfl_xor(qv[q], mm);
      }
    }
    if ((lane & 31) == 0) {
      #pragma unroll
      for (int q = 0; q < 16; ++q) {
        int m = mY + wr * 32 + (q & 3) + 8 * (q >> 2) + 4 * (lane >> 5);
        Part[(size_t)m * 16 + blockIdx.y * 2 + wc] = sv[q];
        Part[(size_t)m * 16 + 8 + blockIdx.y * 2 + wc] = qv[q];
      }
    }
  }

  #pragma unroll
  for (int ct = 0; ct < 2; ++ct) {
    #pragma unroll
    for (int q = 0; q < 16; ++q) {
      int m = mY + wr * 32 + (q & 3) + 8 * (q >> 2) + 4 * (lane >> 5);
      float z = v[ct][q];
      Y[(size_t)m * N + col0 + ct * 32] = z;
      if (EPI == EP_NL3) Yres[(size_t)m * N + col0 + ct * 32] += z;
    }
  }
}

// ---- per-row LN stats from 8 column-block partials -----------------------
__global__ __launch_bounds__(256)
void rowstats(const float* __restrict__ Part, float* __restrict__ mu,
              float* __restrict__ rsd, int M) {
  int m = blockIdx.x * 256 + threadIdx.x;
  if (m >= M) return;
  const float* p = Part + (size_t)m * 16;
  float S = 0.f, Q = 0.f;
  #pragma unroll
  for (int i = 0; i < 8; ++i) { S += p[i]; Q += p[8 + i]; }
  float mm = S * (1.f / 512.f);
  mu[m] = mm;
  rsd[m] = rsqrtf(Q * (1.f / 512.f) - mm * mm + 1e-5f);
}

// ---- apply LN+relu to 6 H2 rows and sum per segment ----------------------
__global__ __launch_bounds__(256)
void h2_sum_ln(const float* __restrict__ H2, const float* __restrict__ mu,
               const float* __restrict__ rsd, const float* __restrict__ g,
               const float* __restrict__ bn, float* __restrict__ SS, int nrows) {
  int id = blockIdx.x * 256 + threadIdx.x;
  if (id >= nrows * 128) return;
  int ln = id >> 7, c4 = (id & 127) * 4;
  float4 gv = *(const float4*)(g + c4);
  float4 bv = *(const float4*)(bn + c4);
  float ax = 0.f, ay = 0.f, az = 0.f, aw = 0.f;
  #pragma unroll
  for (int r = 0; r < 6; ++r) {
    int row = ln * 6 + r;
    float4 y = *(const float4*)(H2 + (size_t)row * 512 + c4);
    float m = mu[row], rs = rsd[row];
    ax += fmaxf((y.x - m) * rs * gv.x + bv.x, 0.f);
    ay += fmaxf((y.y - m) * rs * gv.y + bv.y, 0.f);
    az += fmaxf((y.z - m) * rs * gv.z + bv.z, 0.f);
    aw += fmaxf((y.w - m) * rs * gv.w + bv.w, 0.f);
  }
  float4 o; o.x = ax; o.y = ay; o.z = az; o.w = aw;
  *(float4*)(SS + (size_t)ln * 512 + c4) = o;
}

// ---- launcher ------------------------------------------------------------
extern "C" void kernel_launch(void* const* d_in, const int* in_sizes, int n_in,
                              void* d_out, int out_size, void* d_ws, size_t ws_size,
                              hipStream_t stream) {
  (void)in_sizes; (void)n_in; (void)out_size;
  const float* states = (const float*)d_in[0];
  const int* action = (const int*)d_in[1];
  const float* e_w1 = (const float*)d_in[2];
  const float* e_b1 = (const float*)d_in[3];
  const float* e_w2 = (const float*)d_in[4];
  const float* e_b2 = (const float*)d_in[5];
  const float* e_g = (const float*)d_in[6];
  const float* e_bn = (const float*)d_in[7];
  const float* e_w3 = (const float*)d_in[8];
  const float* e_b3 = (const float*)d_in[9];
  const float* n_w1 = (const float*)d_in[10];
  const float* n_b1 = (const float*)d_in[11];
  const float* n_w2 = (const float*)d_in[12];
  const float* n_b2 = (const float*)d_in[13];
  const float* n_g = (const float*)d_in[14];
  const float* n_bn = (const float*)d_in[15];
  const float* n_w3 = (const float*)d_in[16];
  const float* n_b3 = (const float*)d_in[17];

  float* flat = (float*)d_out;                  // [8192][256]
  float* fp = (float*)d_ws;
  float* node = fp;  fp += 2097152;             // [8192][256]
  float* SS = fp;    fp += 4194304;             // [8192][512] (tail rows stay 0)
  float* G = fp;     fp += 4194304;             // [8192][512]
  float* Sb = fp;    fp += 3670016;             // [7168][512]
  float* Tb = fp;    fp += 3670016;             // [7168][512]
  float* Mbuf = fp;  fp += 262144;              // [512][512]  e_w3 @ n_w1g
  float* v6 = fp;    fp += 512;
  float* muE = fp;   fp += 43008;
  float* rsdE = fp;  fp += 43008;
  float* muN = fp;   fp += 8192;
  float* rsdN = fp;  fp += 8192;
  float* PartE = fp; fp += 688128;              // [43008][16]
  float* PartN = fp; fp += 131072;              // [8192][16]
  ushort_t* us = (ushort_t*)fp;
  ushort_t* PeWab = us;  us += 524288;          // K512 N512
  ushort_t* PeWc = us;   us += 262144;          // K256 N512
  ushort_t* PeW2 = us;   us += 524288;          // K512 N512
  ushort_t* Ptmp = us;   us += 524288;          // n_w1g (K512 N512) for M compute
  ushort_t* PnW1M = us;  us += 786432;          // K768 N512 (flat rows | M rows)
  ushort_t* PnW2 = us;   us += 524288;          // K512 N512
  ushort_t* PnW3 = us;   us += 262144;          // K512 N256
  float* H2raw = (float*)us;

  const size_t fixedB = (size_t)((char*)H2raw - (char*)d_ws);
  int nc = 32;
  for (int cand = 1; cand <= 32; cand <<= 1)
    if (fixedB + (43008ull / cand) * 512ull * 4ull <= ws_size) { nc = cand; break; }
  const int spc = 1024 / nc;
  const int epc = spc * 42;

  // ---- one-time prep ----
  prepack<<<1024, 256, 0, stream>>>(e_w1, PeWab, 0, 512, 512);
  prepack<<<512, 256, 0, stream>>>(e_w1 + 262144, PeWc, 0, 256, 512);
  prepack<<<1024, 256, 0, stream>>>(e_w2, PeW2, 0, 512, 512);
  prepack<<<1024, 256, 0, stream>>>(n_w1 + 133120, Ptmp, 0, 512, 512);
  prepack<<<512, 256, 0, stream>>>(n_w1, PnW1M, 0, 256, 512);
  prepack<<<1024, 256, 0, stream>>>(n_w2, PnW2, 0, 512, 512);
  prepack<<<512, 256, 0, stream>>>(n_w3, PnW3, 0, 512, 256);
  // M = e_w3 @ n_w1g  (512x512, K=512)
  gemmT<4, EP_NONE, 0, 0><<<dim3(8, 4), 256, 0, stream>>>(
      e_w3, 512, 8, nullptr, 0, 0, nullptr, nullptr, Ptmp, nullptr, nullptr,
      nullptr, nullptr, nullptr, nullptr, nullptr, nullptr, Mbuf, nullptr, nullptr, 0);
  prepack<<<1024, 256, 0, stream>>>(Mbuf, PnW1M, 256, 512, 512);
  v6k<<<2, 256, 0, stream>>>(e_b3, n_w1, v6);
  hipMemsetAsync(SS + (size_t)NSEG * 512, 0, (size_t)(NNODE - NSEG) * 512 * 4, stream);
  hipMemcpyAsync(flat, states, (size_t)NNODE * 256 * 4, hipMemcpyDeviceToDevice, stream);

  for (int round = 0; round < 8; ++round) {
    // S = flat7@Wa (+ node7@Wb) + b1 ; T = flat7@Wc
    if (round == 0)
      gemmT<4, EP_BIAS, 0, 0><<<dim3(112, 4), 256, 0, stream>>>(
          flat, 256, 4, nullptr, 0, 0, nullptr, nullptr, PeWab, e_b1, nullptr,
          nullptr, nullptr, nullptr, nullptr, nullptr, nullptr, Sb, nullptr, nullptr, 0);
    else
      gemmT<4, EP_BIAS, 0, 0><<<dim3(112, 4), 256, 0, stream>>>(
          flat, 256, 4, node, 256, 4, nullptr, nullptr, PeWab, e_b1, nullptr,
          nullptr, nullptr, nullptr, nullptr, nullptr, nullptr, Sb, nullptr, nullptr, 0);
    gemmT<4, EP_NONE, 0, 0><<<dim3(112, 4), 256, 0, stream>>>(
        flat, 256, 4, nullptr, 0, 0, nullptr, nullptr, PeWc, nullptr, nullptr,
        nullptr, nullptr, nullptr, nullptr, nullptr, nullptr, Tb, nullptr, nullptr, 0);
    // edge layer 2 raw + partials; stats; LN+relu+sum6 into SS (rows < 7168)
    for (int ch = 0; ch < nc; ++ch) {
      gemmT<4, EP_RAWP, 1, 0><<<dim3(epc / 64, 4), 256, 0, stream>>>(
          nullptr, 0, 8, nullptr, 0, 0, Sb, Tb, PeW2, e_b2, nullptr,
          nullptr, nullptr, nullptr, nullptr, nullptr, nullptr,
          H2raw, nullptr, PartE, ch * epc);
      rowstats<<<(epc + 255) / 256, 256, 0, stream>>>(PartE, muE, rsdE, epc);
      h2_sum_ln<<<(spc * 7 * 128) / 256, 256, 0, stream>>>(
          H2raw, muE, rsdE, e_g, e_bn, SS + (size_t)ch * spc * 7 * 512, spc * 7);
    }
    // node L1 (agg GEMM folded in): relu(flat@W1f + SS@M + b1 + [m<7168]v6 + av)
    gemmT<4, EP_NL1, 0, 0><<<dim3(128, 4), 256, 0, stream>>>(
        flat, 256, 4, SS, 512, 8, nullptr, nullptr, PnW1M, n_b1, v6,
        (round == 0) ? action : nullptr, n_w1,
        nullptr, nullptr, nullptr, nullptr, G, nullptr, nullptr, 0);
    // node L2 raw + partials: G -> G (in-place, same-rows safe); stats
    gemmT<4, EP_RAWP, 0, 0><<<dim3(128, 4), 256, 0, stream>>>(
        G, 512, 8, nullptr, 0, 0, nullptr, nullptr, PnW2, n_b2, nullptr,
        nullptr, nullptr, nullptr, nullptr, nullptr, nullptr, G, nullptr, PartN, 0);
    rowstats<<<32, 256, 0, stream>>>(PartN, muN, rsdN, 8192);
    // node L3 (+LN on staging) + residual: G -> node, flat +=
    gemmT<2, EP_NL3, 0, 1><<<dim3(128, 2), 256, 0, stream>>>(
        G, 512, 8, nullptr, 0, 0, nullptr, nullptr, PnW3, n_b3, nullptr,
        nullptr, nullptr, muN, rsdN, n_g, n_bn, node, flat, nullptr, 0);
  }
}